// Round 10
// baseline (87.870 us; speedup 1.0000x reference)
//
#include <hip/hip_runtime.h>
#include <hip/hip_bf16.h>

#define Bn 16
#define Sn 2048
#define Hn 768
#define Dn 128
#define AT 8
#define IT 32
#define NSEG (Bn*AT*IT)      // 4096

typedef __attribute__((ext_vector_type(4))) float f32x4;
typedef __attribute__((ext_vector_type(4))) int   i32x4;
typedef __attribute__((ext_vector_type(8))) short bf16x8;
typedef __attribute__((ext_vector_type(4))) short s16x4;

__device__ __forceinline__ unsigned short f2bf(float f){
  __hip_bfloat16 h = __float2bfloat16(f);   // HW RNE
  return *reinterpret_cast<unsigned short*>(&h);
}

// ---- kernel 0: W [768][128] f32 -> Wt [128][768] bf16, LDS-tiled transpose ----
__global__ __launch_bounds__(256) void k_prep(const float* __restrict__ W,
                                              unsigned short* __restrict__ Wt){
  __shared__ float sT[64][65];
  const int tid = threadIdx.x;
  const int k0 = (blockIdx.x % 12) * 64;
  const int d0 = (blockIdx.x / 12) * 64;
  const int rr = tid >> 4;          // 0..15
  const int cg = tid & 15;          // 0..15 -> 4 cols

  #pragma unroll
  for (int p = 0; p < 4; ++p){
    int k = rr + p*16;
    f32x4 v = *(const f32x4*)&W[(size_t)(k0 + k)*Dn + d0 + cg*4];
    sT[k][cg*4+0] = v[0]; sT[k][cg*4+1] = v[1];
    sT[k][cg*4+2] = v[2]; sT[k][cg*4+3] = v[3];
  }
  __syncthreads();
  #pragma unroll
  for (int p = 0; p < 4; ++p){
    int d = rr + p*16;
    s16x4 t;
    #pragma unroll
    for (int j = 0; j < 4; ++j) t[j] = (short)f2bf(sT[cg*4+j][d]);
    *(s16x4*)&Wt[(size_t)(d0 + d)*Hn + k0 + cg*4] = t;
  }
}

// ---- kernel 1: h = X @ W + b — barrier-less, LDS-free, DEEP register pipeline ----
// BM=32, grid 1024 = 4 WGs/CU = 16 waves/CU (2x R7's TLP). Wave (wm,wn) owns
// 16 rows x 64 cols. A staged depth-3, B depth-2, fully unrolled (compile-time
// set indices). Consuming step s only waits on loads issued at s-2 -> ~2-step
// x 4-waves/SIMD cover (~1200cy) > 900cy HBM latency. Zero LDS, zero barriers:
// no vmcnt(0) drains, no lock-step coupling. K-order per output element is
// identical to all previous rounds -> bitwise-same result.
__global__ __launch_bounds__(256, 4) void k_gemm(const float* __restrict__ X,
        const unsigned short* __restrict__ Wt, const float* __restrict__ bias,
        float* __restrict__ Hout){
  const int tid  = threadIdx.x;
  const int lane = tid & 63;
  const int wave = tid >> 6;
  const int wm = wave >> 1, wn = wave & 1;
  const int m0 = blockIdx.x * 32;
  const int r16 = lane & 15, kg = lane >> 4;

  const float* Ap = X + (size_t)(m0 + wm*16 + r16)*Hn + kg*8;
  const unsigned short* Bp[4];
  #pragma unroll
  for (int ni=0;ni<4;ni++)
    Bp[ni] = Wt + (size_t)(wn*64 + ni*16 + r16)*Hn + kg*8;

  f32x4  aL[3][2];   // A raw f32, depth-3 ring [set][lo/hi]
  bf16x8 bs[2][4];   // B frags,   depth-2 ring [set][ni]
  f32x4  acc[4];
  #pragma unroll
  for (int ni=0;ni<4;ni++) acc[ni] = (f32x4){0.f,0.f,0.f,0.f};

  // prologue: A for steps 0,1,2 ; B for steps 0,1
  #pragma unroll
  for (int s=0;s<3;++s){
    aL[s][0] = *(const f32x4*)(Ap + s*32);
    aL[s][1] = *(const f32x4*)(Ap + s*32 + 4);
  }
  #pragma unroll
  for (int s=0;s<2;++s)
    #pragma unroll
    for (int ni=0;ni<4;ni++)
      bs[s][ni] = *(const bf16x8*)(Bp[ni] + s*32);

  #pragma unroll
  for (int s=0; s<24; ++s){
    const int sa = s % 3;          // compile-time after full unroll
    const int sb = s & 1;
    // consume: convert A(s) and run 4 MFMAs against B(s)
    f32x4 lo = aL[sa][0], hi = aL[sa][1];
    bf16x8 af;
    af[0]=(short)f2bf(lo[0]); af[1]=(short)f2bf(lo[1]);
    af[2]=(short)f2bf(lo[2]); af[3]=(short)f2bf(lo[3]);
    af[4]=(short)f2bf(hi[0]); af[5]=(short)f2bf(hi[1]);
    af[6]=(short)f2bf(hi[2]); af[7]=(short)f2bf(hi[3]);
    #pragma unroll
    for (int ni=0;ni<4;ni++)
      acc[ni] = __builtin_amdgcn_mfma_f32_16x16x32_bf16(af, bs[sb][ni], acc[ni], 0, 0, 0);
    // reissue into the freed sets: A(s+3), B(s+2)
    if (s+3 < 24){
      aL[sa][0] = *(const f32x4*)(Ap + (s+3)*32);
      aL[sa][1] = *(const f32x4*)(Ap + (s+3)*32 + 4);
    }
    if (s+2 < 24){
      #pragma unroll
      for (int ni=0;ni<4;ni++)
        bs[sb][ni] = *(const bf16x8*)(Bp[ni] + (s+2)*32);
    }
  }

  // epilogue: C/D layout col=lane&15, row=(lane>>4)*4+r  (m89-verified)
  #pragma unroll
  for (int ni=0;ni<4;ni++){
    int col = wn*64 + ni*16 + r16;
    float bb = bias[col];
    int row0 = m0 + wm*16 + kg*4;
    #pragma unroll
    for (int r=0;r<4;r++)
      Hout[(size_t)(row0 + r)*Dn + col] = acc[ni][r] + bb;
  }
}

// ---- kernel 2: per-(batch,attr,dim-half) segment mean -> pooled + empty ----
__global__ __launch_bounds__(256) void k_scan(const int* __restrict__ attr,
        const int* __restrict__ item, const float* __restrict__ Hsrc,
        float* __restrict__ pooled, float* __restrict__ empty){
  __shared__ float ssum[4][IT][64];   // 32 KB, one slab per wave
  __shared__ int   slist[4][512];     // 8 KB ordered match lists
  __shared__ int   scnt[IT];

  const int wg  = blockIdx.x;        // (b*8 + a)*2 + dh
  const int dh  = wg & 1;
  const int a   = (wg >> 1) & 7;
  const int b   = wg >> 4;
  const int tid = threadIdx.x;       // 0..255
  const int wv  = tid >> 6;
  const int lane = tid & 63;

  #pragma unroll
  for (int i = 0; i < IT; ++i) ssum[wv][i][lane] = 0.f;
  if (tid < IT) scnt[tid] = 0;

  const int tok0 = wv * 512;
  const int gbase = b * Sn;
  int nm = 0;
  #pragma unroll
  for (int g = 0; g < 8; ++g){
    int tok = tok0 + g*64 + lane;
    int avv = attr[gbase + tok], ivv = item[gbase + tok];
    bool m = (avv == a+1) && (ivv >= 1) && (ivv <= IT);
    unsigned long long mask = __ballot(m);
    int pos = nm + __popcll(mask & ((1ull << lane) - 1ull));
    if (m) slist[wv][pos] = ((ivv-1) << 16) | tok;
    nm += __popcll(mask);
  }
  __syncthreads();   // scnt zeros visible

  for (int e = lane; e < nm; e += 64) atomicAdd(&scnt[slist[wv][e] >> 16], 1);

  const float* hb = Hsrc + (size_t)b*Sn*Dn + dh*64 + lane;
  int e = 0;
  for (; e + 8 <= nm; e += 8){
    int idx[8]; float v[8];
    #pragma unroll
    for (int j=0;j<8;j++) idx[j] = slist[wv][e+j];
    #pragma unroll
    for (int j=0;j<8;j++) v[j] = hb[(size_t)(idx[j] & 0xffff)*Dn];
    #pragma unroll
    for (int j=0;j<8;j++) ssum[wv][idx[j]>>16][lane] += v[j];
  }
  for (; e < nm; ++e){
    int idx = slist[wv][e];
    ssum[wv][idx>>16][lane] += hb[(size_t)(idx & 0xffff)*Dn];
  }
  __syncthreads();

  float* outp = pooled + (size_t)(b*AT + a)*IT*Dn + dh*64;
  for (int o = tid; o < IT*64; o += 256){
    int i = o >> 6, d = o & 63;
    float s = ssum[0][i][d] + ssum[1][i][d] + ssum[2][i][d] + ssum[3][i][d];
    int cnt = scnt[i];
    outp[i*Dn + d] = s / (float)(cnt > 0 ? cnt : 1);
  }
  if (dh == 0 && tid < IT)
    empty[(b*AT + a)*IT + tid] = (scnt[tid] == 0) ? 1.f : 0.f;
}

extern "C" void kernel_launch(void* const* d_in, const int* in_sizes, int n_in,
                              void* d_out, int out_size, void* d_ws, size_t ws_size,
                              hipStream_t stream) {
  const float* hidden = (const float*)d_in[1];
  const int*   attr   = (const int*)  d_in[2];
  const int*   item   = (const int*)  d_in[3];
  const float* W      = (const float*)d_in[4];
  const float* bias   = (const float*)d_in[5];

  float* pooled = (float*)d_out;
  float* empty  = pooled + (size_t)NSEG*Dn;          // +524288
  float* Hout   = empty  + NSEG;                     // +4096

  unsigned short* Wt = (unsigned short*)d_ws;

  k_prep<<<24, 256, 0, stream>>>(W, Wt);
  k_gemm<<<(Bn*Sn)/32, 256, 0, stream>>>(hidden, Wt, bias, Hout);
  k_scan<<<Bn*AT*2, 256, 0, stream>>>(attr, item, Hout, pooled, empty);
}

// Round 11
// 40.504 us; speedup vs baseline: 2.1695x; 2.1695x over previous
//
#include <hip/hip_runtime.h>
#include <hip/hip_bf16.h>

#define Bn 16
#define Sn 2048
#define Hn 768
#define Dn 128
#define AT 8
#define IT 32
#define NSEG (Bn*AT*IT)      // 4096

typedef __attribute__((ext_vector_type(4))) float f32x4;
typedef __attribute__((ext_vector_type(4))) int   i32x4;
typedef __attribute__((ext_vector_type(8))) short bf16x8;
typedef __attribute__((ext_vector_type(4))) short s16x4;

__device__ __forceinline__ unsigned short f2bf(float f){
  __hip_bfloat16 h = __float2bfloat16(f);   // HW RNE
  return *reinterpret_cast<unsigned short*>(&h);
}

// ---- kernel 0: W [768][128] f32 -> Wt [128][768] bf16, LDS-tiled transpose ----
__global__ __launch_bounds__(256) void k_prep(const float* __restrict__ W,
                                              unsigned short* __restrict__ Wt){
  __shared__ float sT[64][65];
  const int tid = threadIdx.x;
  const int k0 = (blockIdx.x % 12) * 64;
  const int d0 = (blockIdx.x / 12) * 64;
  const int rr = tid >> 4;          // 0..15
  const int cg = tid & 15;          // 0..15 -> 4 cols

  #pragma unroll
  for (int p = 0; p < 4; ++p){
    int k = rr + p*16;
    f32x4 v = *(const f32x4*)&W[(size_t)(k0 + k)*Dn + d0 + cg*4];
    sT[k][cg*4+0] = v[0]; sT[k][cg*4+1] = v[1];
    sT[k][cg*4+2] = v[2]; sT[k][cg*4+3] = v[3];
  }
  __syncthreads();
  #pragma unroll
  for (int p = 0; p < 4; ++p){
    int d = rr + p*16;
    s16x4 t;
    #pragma unroll
    for (int j = 0; j < 4; ++j) t[j] = (short)f2bf(sT[cg*4+j][d]);
    *(s16x4*)&Wt[(size_t)(d0 + d)*Hn + k0 + cg*4] = t;
  }
}

// ---- kernel 1: h = X @ W + b  (bf16 MFMA 16x16x32) ----
// R3 skeleton, four fixes:
//  1. Staging WRITES conflict-free: thread=(r0,kq) -> 4 rows x 16B f32 (4x256B
//     DRAM segments/inst); bf16 write at row*128 + (((kq>>1)^(row&7))<<4) +
//     ((kq&1)<<3) — each 16-lane phase covers all 32 banks once (R3's write
//     offsets were closed under its swizzle -> 16-way conflict, R6: 9.8M cyc).
//  2. B in registers (prefetch 1 step ahead from L2-resident Wt) — no B LDS.
//  3. FIFO-correct: per step issue B(s+1) then A(s+2); MFMA's wait for B(s)
//     leaves 16 loads in flight; cvt's wait for A(s+1) leaves 12.
//  4. Raw s_barrier + lgkmcnt(0) only (no vmcnt drain) + sched_barrier walls
//     (prevents the R10 compiler pipeline-collapse).
// Read path + MFMA order identical to R3 -> bitwise-same h.
__global__ __launch_bounds__(256) void k_gemm(const float* __restrict__ X,
        const unsigned short* __restrict__ Wt, const float* __restrict__ bias,
        float* __restrict__ Hout){
  __shared__ unsigned char sA[2][64*128];   // bf16, swizzled, 2 x 8 KB
  const int tid  = threadIdx.x;
  const int lane = tid & 63;
  const int wave = tid >> 6;
  const int m0   = blockIdx.x * 64;
  const int r16  = lane & 15, kg = lane >> 4;

  // staging map: thread -> rows r0+i*16, f32 chunk kq (16B)
  const int r0 = tid >> 4;          // 0..15
  const int kq = tid & 15;          // 0..15
  const float* Ap = X + (size_t)(m0 + r0)*Hn + kq*4;
  int awoff[4];
  #pragma unroll
  for (int i=0;i<4;i++){
    int row = r0 + i*16;
    awoff[i] = row*128 + ((((kq>>1) ^ (row&7))<<4) | ((kq&1)<<3));
  }

  // B pointers: col = wave*32 + ni*16 + r16, k-base kg*8
  const unsigned short* Bp[2];
  #pragma unroll
  for (int ni=0;ni<2;ni++)
    Bp[ni] = Wt + (size_t)(wave*32 + ni*16 + r16)*Hn + kg*8;

  // A fragment read addrs (identical to R3; conflict-free)
  int abase[4], aswz[4];
  #pragma unroll
  for (int mi=0;mi<4;mi++){
    int row = mi*16 + r16;
    abase[mi] = row*128; aswz[mi] = (row&7)<<4;
  }
  const int kblk = kg*16;

  f32x4 acc[4][2];
  #pragma unroll
  for (int mi=0;mi<4;mi++)
    #pragma unroll
    for (int ni=0;ni<2;ni++) acc[mi][ni] = (f32x4){0.f,0.f,0.f,0.f};

  f32x4  av[2][4];   // A(k) lives in set k&1
  bf16x8 bv[2][4];   // B(k) lives in set k&1, [ks*2+ni]

  // prologue (issue order: A(0), B(0), A(1) — cvt's wait leaves B(0)+A(1) flying)
  #pragma unroll
  for (int i=0;i<4;i++) av[0][i] = *(const f32x4*)(Ap + (size_t)i*16*Hn);
  #pragma unroll
  for (int ks=0;ks<2;ks++)
    #pragma unroll
    for (int ni=0;ni<2;ni++)
      bv[0][ks*2+ni] = *(const bf16x8*)(Bp[ni] + ks*32);
  #pragma unroll
  for (int i=0;i<4;i++) av[1][i] = *(const f32x4*)(Ap + (size_t)i*16*Hn + 64);
  #pragma unroll
  for (int i=0;i<4;i++){
    s16x4 t;
    t[0]=(short)f2bf(av[0][i][0]); t[1]=(short)f2bf(av[0][i][1]);
    t[2]=(short)f2bf(av[0][i][2]); t[3]=(short)f2bf(av[0][i][3]);
    *(s16x4*)&sA[0][awoff[i]] = t;
  }
  asm volatile("s_waitcnt lgkmcnt(0)" ::: "memory");
  __builtin_amdgcn_s_barrier();
  __builtin_amdgcn_sched_barrier(0);

  #pragma unroll
  for (int s=0; s<12; ++s){
    const int cb = s&1;           // current LDS buf + B/A parity for step s
    const int nb = cb^1;
    // (1) B(s+1) — issued a full step before use
    if (s < 11){
      #pragma unroll
      for (int ks=0;ks<2;ks++)
        #pragma unroll
        for (int ni=0;ni<2;ni++)
          bv[nb][ks*2+ni] = *(const bf16x8*)(Bp[ni] + (s+1)*64 + ks*32);
    }
    // (2) A(s+2) into freed set cb — two steps of cover
    if (s < 10){
      #pragma unroll
      for (int i=0;i<4;i++)
        av[cb][i] = *(const f32x4*)(Ap + (size_t)i*16*Hn + (s+2)*64);
    }
    // (3) compute step s: sA[cb] x bv[cb]  (waits: lgkm for ds_read, vmcnt(16) for B(s))
    #pragma unroll
    for (int ks=0;ks<2;ks++){
      bf16x8 af[4];
      #pragma unroll
      for (int mi=0;mi<4;mi++)
        af[mi] = *(const bf16x8*)&sA[cb][abase[mi] + ((ks*64 + kblk) ^ aswz[mi])];
      #pragma unroll
      for (int mi=0;mi<4;mi++)
        #pragma unroll
        for (int ni=0;ni<2;ni++)
          acc[mi][ni] = __builtin_amdgcn_mfma_f32_16x16x32_bf16(af[mi], bv[cb][ks*2+ni], acc[mi][ni], 0, 0, 0);
    }
    // (4) cvt + conflict-free write of A(s+1) (waits vmcnt(12): B(s+1)+A(s+2) stay in flight)
    if (s < 11){
      #pragma unroll
      for (int i=0;i<4;i++){
        s16x4 t;
        t[0]=(short)f2bf(av[nb][i][0]); t[1]=(short)f2bf(av[nb][i][1]);
        t[2]=(short)f2bf(av[nb][i][2]); t[3]=(short)f2bf(av[nb][i][3]);
        *(s16x4*)&sA[nb][awoff[i]] = t;
      }
      // (5) LDS-only drain + barrier; loads stay in flight across it
      asm volatile("s_waitcnt lgkmcnt(0)" ::: "memory");
      __builtin_amdgcn_s_barrier();
      __builtin_amdgcn_sched_barrier(0);
    }
  }

  // epilogue: C/D layout col=lane&15, row=(lane>>4)*4+r  (m89-verified)
  #pragma unroll
  for (int ni=0;ni<2;ni++){
    int col = wave*32 + ni*16 + r16;
    float bb = bias[col];
    #pragma unroll
    for (int mi=0;mi<4;mi++){
      int row0 = m0 + mi*16 + kg*4;
      #pragma unroll
      for (int r=0;r<4;r++)
        Hout[(size_t)(row0 + r)*Dn + col] = acc[mi][ni][r] + bb;
    }
  }
}

// ---- kernel 2: per-(batch,attr,dim-half) segment mean -> pooled + empty ----
__global__ __launch_bounds__(256) void k_scan(const int* __restrict__ attr,
        const int* __restrict__ item, const float* __restrict__ Hsrc,
        float* __restrict__ pooled, float* __restrict__ empty){
  __shared__ float ssum[4][IT][64];   // 32 KB, one slab per wave
  __shared__ int   slist[4][512];     // 8 KB ordered match lists
  __shared__ int   scnt[IT];

  const int wg  = blockIdx.x;        // (b*8 + a)*2 + dh
  const int dh  = wg & 1;
  const int a   = (wg >> 1) & 7;
  const int b   = wg >> 4;
  const int tid = threadIdx.x;       // 0..255
  const int wv  = tid >> 6;
  const int lane = tid & 63;

  #pragma unroll
  for (int i = 0; i < IT; ++i) ssum[wv][i][lane] = 0.f;
  if (tid < IT) scnt[tid] = 0;

  const int tok0 = wv * 512;
  const int gbase = b * Sn;
  int nm = 0;
  #pragma unroll
  for (int g = 0; g < 8; ++g){
    int tok = tok0 + g*64 + lane;
    int avv = attr[gbase + tok], ivv = item[gbase + tok];
    bool m = (avv == a+1) && (ivv >= 1) && (ivv <= IT);
    unsigned long long mask = __ballot(m);
    int pos = nm + __popcll(mask & ((1ull << lane) - 1ull));
    if (m) slist[wv][pos] = ((ivv-1) << 16) | tok;
    nm += __popcll(mask);
  }
  __syncthreads();   // scnt zeros visible

  for (int e = lane; e < nm; e += 64) atomicAdd(&scnt[slist[wv][e] >> 16], 1);

  const float* hb = Hsrc + (size_t)b*Sn*Dn + dh*64 + lane;
  int e = 0;
  for (; e + 8 <= nm; e += 8){
    int idx[8]; float v[8];
    #pragma unroll
    for (int j=0;j<8;j++) idx[j] = slist[wv][e+j];
    #pragma unroll
    for (int j=0;j<8;j++) v[j] = hb[(size_t)(idx[j] & 0xffff)*Dn];
    #pragma unroll
    for (int j=0;j<8;j++) ssum[wv][idx[j]>>16][lane] += v[j];
  }
  for (; e < nm; ++e){
    int idx = slist[wv][e];
    ssum[wv][idx>>16][lane] += hb[(size_t)(idx & 0xffff)*Dn];
  }
  __syncthreads();

  float* outp = pooled + (size_t)(b*AT + a)*IT*Dn + dh*64;
  for (int o = tid; o < IT*64; o += 256){
    int i = o >> 6, d = o & 63;
    float s = ssum[0][i][d] + ssum[1][i][d] + ssum[2][i][d] + ssum[3][i][d];
    int cnt = scnt[i];
    outp[i*Dn + d] = s / (float)(cnt > 0 ? cnt : 1);
  }
  if (dh == 0 && tid < IT)
    empty[(b*AT + a)*IT + tid] = (scnt[tid] == 0) ? 1.f : 0.f;
}

extern "C" void kernel_launch(void* const* d_in, const int* in_sizes, int n_in,
                              void* d_out, int out_size, void* d_ws, size_t ws_size,
                              hipStream_t stream) {
  const float* hidden = (const float*)d_in[1];
  const int*   attr   = (const int*)  d_in[2];
  const int*   item   = (const int*)  d_in[3];
  const float* W      = (const float*)d_in[4];
  const float* bias   = (const float*)d_in[5];

  float* pooled = (float*)d_out;
  float* empty  = pooled + (size_t)NSEG*Dn;          // +524288
  float* Hout   = empty  + NSEG;                     // +4096

  unsigned short* Wt = (unsigned short*)d_ws;

  k_prep<<<24, 256, 0, stream>>>(W, Wt);
  k_gemm<<<(Bn*Sn)/64, 256, 0, stream>>>(hidden, Wt, bias, Hout);
  k_scan<<<Bn*AT*2, 256, 0, stream>>>(attr, item, Hout, pooled, empty);
}